// Round 11
// baseline (221.999 us; speedup 1.0000x reference)
//
#include <hip/hip_runtime.h>

typedef float  f32x4 __attribute__((ext_vector_type(4)));
typedef short  s16x8 __attribute__((ext_vector_type(8)));
typedef unsigned short u16;
typedef unsigned int   u32;

constexpr int D    = 128;
constexpr int DOUT = 64;
constexpr int NBLK = 256;   // edge chunks for level-1 hist/place
constexpr int BSH  = 7;     // 128 rows per bucket
constexpr int BROWS = 128;
constexpr int SCAP = 5120;  // staged edges per bucket in sort (40KB LDS)
constexpr int REPACK_BLKS = 44; // ceil(11264/256)

// ---------------------------------------------------------------------------
__device__ inline u16 f2bf(float f) {
    u32 x = __float_as_uint(f);
    u32 r = (x + 0x7fffu + ((x >> 16) & 1u)) >> 16;
    return (u16)r;
}
__device__ inline float bflo(u32 u) { return __uint_as_float(u << 16); }
__device__ inline float bfhi(u32 u) { return __uint_as_float(u & 0xffff0000u); }

// ---------------------------------------------------------------------------
// Weight repack body (6 weights -> MFMA B-fragment-linear bf16), t in [0,11264)
// ---------------------------------------------------------------------------
__device__ inline void repack_body(int t,
    const float* __restrict__ W1,  u16* __restrict__ W1f,
    const float* __restrict__ Wm1, u16* __restrict__ Wm1f,
    const float* __restrict__ W2,  u16* __restrict__ W2f,
    const float* __restrict__ Wm2, u16* __restrict__ Wm2f,
    const float* __restrict__ Wh2, u16* __restrict__ Wh2f,
    const float* __restrict__ Wh1, u16* __restrict__ Wh1f)
{
    const float* W; u16* Wf; int NT, NOUT, base;
    if      (t < 2048)  { W = W1;  Wf = W1f;  NT = 8; NOUT = 128; base = 0; }
    else if (t < 4096)  { W = Wm1; Wf = Wm1f; NT = 8; NOUT = 128; base = 2048; }
    else if (t < 5120)  { W = W2;  Wf = W2f;  NT = 4; NOUT = 64;  base = 4096; }
    else if (t < 6144)  { W = Wm2; Wf = Wm2f; NT = 4; NOUT = 64;  base = 5120; }
    else if (t < 7168)  { W = Wh2; Wf = Wh2f; NT = 4; NOUT = 64;  base = 6144; }
    else                { W = Wh1; Wf = Wh1f; NT = 8; NOUT = 128; base = 7168; }
    int lt   = t - base;
    int kk   = lt / (NT * 64);
    int rem  = lt % (NT * 64);
    int nt   = rem / 64;
    int lane = rem % 64;
    int k0 = kk * 32 + ((lane >> 4) << 3);
    int c  = nt * 16 + (lane & 15);
    #pragma unroll
    for (int j = 0; j < 8; ++j)
        Wf[(size_t)lt * 8 + j] = f2bf(W[(size_t)(k0 + j) * NOUT + c]);
}

// K1: fused repack (blocks [0,44)) + level-1 bucket histogram (blocks [44,...))
__global__ __launch_bounds__(256) void fused_prep(
    const float* __restrict__ W1,  u16* __restrict__ W1f,
    const float* __restrict__ Wm1, u16* __restrict__ Wm1f,
    const float* __restrict__ W2,  u16* __restrict__ W2f,
    const float* __restrict__ Wm2, u16* __restrict__ Wm2f,
    const float* __restrict__ Wh2, u16* __restrict__ Wh2f,
    const float* __restrict__ Wh1, u16* __restrict__ Wh1f,
    const int* __restrict__ dst, int* __restrict__ C, int E, int NBUK, int CE)
{
    __shared__ int h[512];
    if (blockIdx.x < REPACK_BLKS) {
        int t = blockIdx.x * 256 + threadIdx.x;
        if (t < 11264)
            repack_body(t, W1, W1f, Wm1, Wm1f, W2, W2f, Wm2, Wm2f, Wh2, Wh2f, Wh1, Wh1f);
        return;
    }
    int blk = blockIdx.x - REPACK_BLKS;
    for (int i = threadIdx.x; i < NBUK; i += 256) h[i] = 0;
    __syncthreads();
    int e0 = blk * CE, e1 = min(E, e0 + CE);
    for (int e = e0 + threadIdx.x; e < e1; e += 256) {
        int d = __builtin_nontemporal_load(dst + e);
        atomicAdd(&h[d >> BSH], 1);
    }
    __syncthreads();
    for (int i = threadIdx.x; i < NBUK; i += 256)
        C[i * NBLK + blk] = h[i];
}

// ---------------------------------------------------------------------------
__global__ __launch_bounds__(1024) void scan1_kernel(
    int* __restrict__ data, int* __restrict__ bsum, int n)
{
    __shared__ int sm[1024];
    int tid = threadIdx.x;
    int i = blockIdx.x * 1024 + tid;
    int v = (i < n) ? data[i] : 0;
    sm[tid] = v;
    __syncthreads();
    #pragma unroll
    for (int off = 1; off < 1024; off <<= 1) {
        int t = (tid >= off) ? sm[tid - off] : 0;
        __syncthreads();
        sm[tid] += t;
        __syncthreads();
    }
    if (i < n) data[i] = sm[tid] - v;   // exclusive within chunk
    if (tid == 1023) bsum[blockIdx.x] = sm[1023];
}

__global__ __launch_bounds__(1024) void scan_carry(
    const int* __restrict__ in, int* __restrict__ outExc, int n)
{
    __shared__ int sm[1024];
    __shared__ int s_carry;
    int tid = threadIdx.x;
    if (tid == 0) s_carry = 0;
    __syncthreads();
    for (int base = 0; base < n; base += 1024) {
        int i = base + tid;
        int v = (i < n) ? in[i] : 0;
        sm[tid] = v;
        __syncthreads();
        for (int off = 1; off < 1024; off <<= 1) {
            int t = (tid >= off) ? sm[tid - off] : 0;
            __syncthreads();
            sm[tid] += t;
            __syncthreads();
        }
        int carry = s_carry;
        if (i < n) outExc[i] = carry + sm[tid] - v;
        __syncthreads();
        if (tid == 1023) s_carry = carry + sm[1023];
        __syncthreads();
    }
}

// ---------------------------------------------------------------------------
// MFMA building blocks. A tiles (global-staged): padded stride 136 (stagger
// for per-lane-row MFMA reads). B/bounce tiles: compact pow2 stride + XOR
// swizzle col^((row&7)<<3) so both MFMA re-reads and b128 copy are clean.
// All tiles wave-private: no barriers.
// ---------------------------------------------------------------------------
template<int WIDTH, int SA>
__device__ inline void stage_tile(u16* Atile, const u16* __restrict__ src,
                                  int rowbase, int nN, int lane, int colOff)
{
    constexpr int BPR   = WIDTH * 2;
    constexpr int ITERS = (16 * BPR) / 1024;
    #pragma unroll
    for (int it = 0; it < ITERS; ++it) {
        int flat = it * 1024 + lane * 16;
        int row  = flat / BPR;
        int colS = (flat % BPR) >> 1;
        int4 v = make_int4(0, 0, 0, 0);
        int gr = rowbase + row;
        if (gr < nN)
            v = *reinterpret_cast<const int4*>(src + (size_t)gr * WIDTH + colS);
        *reinterpret_cast<int4*>(Atile + row * SA + colOff + colS) = v;
    }
}

// stage 16x128 fp32 tile -> bf16 LDS (fused convert, nt source)
template<int SA>
__device__ inline void stage_cvt_tile(u16* Atile, const float* __restrict__ src,
                                      int rowbase, int nN, int lane)
{
    #pragma unroll
    for (int it = 0; it < 8; ++it) {
        int flat = it * 1024 + lane * 16;
        int row  = flat >> 9;
        int c4   = (flat & 511) >> 2;
        f32x4 v = (f32x4){0.f, 0.f, 0.f, 0.f};
        int gr = rowbase + row;
        if (gr < nN)
            v = __builtin_nontemporal_load(
                    reinterpret_cast<const f32x4*>(src + (size_t)gr * 128 + c4));
        u32 p0 = (u32)f2bf(v.x) | ((u32)f2bf(v.y) << 16);
        u32 p1 = (u32)f2bf(v.z) | ((u32)f2bf(v.w) << 16);
        *reinterpret_cast<u32*>(Atile + row * SA + c4)     = p0;
        *reinterpret_cast<u32*>(Atile + row * SA + c4 + 2) = p1;
    }
}

template<int NT>
__device__ inline void init_acc(f32x4* acc, const float* __restrict__ bias, int lane)
{
    #pragma unroll
    for (int nt = 0; nt < NT; ++nt) {
        float bv = bias ? bias[nt * 16 + (lane & 15)] : 0.f;
        acc[nt] = (f32x4){bv, bv, bv, bv};
    }
}

// MFMA pass, A operand from padded (unswizzled) tile
template<int KK, int NT, int SA>
__device__ inline void mfma_pass(const u16* Atile, const u16* __restrict__ Wf,
                                 int lane, f32x4* acc)
{
    const u16* ap = Atile + (lane & 15) * SA + ((lane >> 4) << 3);
    #pragma unroll
    for (int kk = 0; kk < KK; ++kk) {
        s16x8 a = *reinterpret_cast<const s16x8*>(ap + kk * 32);
        #pragma unroll
        for (int nt = 0; nt < NT; ++nt) {
            s16x8 b = *reinterpret_cast<const s16x8*>(Wf + ((size_t)(kk * NT + nt) * 64 + lane) * 8);
            acc[nt] = __builtin_amdgcn_mfma_f32_16x16x32_bf16(a, b, acc[nt], 0, 0, 0);
        }
    }
}

// MFMA pass, A operand from compact swizzled tile (stride W, col^((row&7)<<3))
template<int KK, int NT, int W>
__device__ inline void mfma_pass_swz(const u16* Bt, const u16* __restrict__ Wf,
                                     int lane, f32x4* acc)
{
    int row = lane & 15;
    int cb  = (lane >> 4) << 3;
    int sw  = (row & 7) << 3;
    #pragma unroll
    for (int kk = 0; kk < KK; ++kk) {
        s16x8 a = *reinterpret_cast<const s16x8*>(Bt + row * W + ((cb + kk * 32) ^ sw));
        #pragma unroll
        for (int nt = 0; nt < NT; ++nt) {
            s16x8 b = *reinterpret_cast<const s16x8*>(Wf + ((size_t)(kk * NT + nt) * 64 + lane) * 8);
            acc[nt] = __builtin_amdgcn_mfma_f32_16x16x32_bf16(a, b, acc[nt], 0, 0, 0);
        }
    }
}

// store C fragments into compact swizzled u16 tile (stride NOUT, pow2)
template<int NT, int NOUT, bool RELU>
__device__ inline void store_c_swz(u16* Bt, f32x4* acc, int lane)
{
    int r0 = (lane >> 4) << 2;
    int c  = lane & 15;
    #pragma unroll
    for (int nt = 0; nt < NT; ++nt)
        #pragma unroll
        for (int i = 0; i < 4; ++i) {
            int row = r0 + i;
            int col = (nt * 16 + c) ^ ((row & 7) << 3);
            float v = acc[nt][i];
            if (RELU) v = fmaxf(v, 0.f);
            Bt[row * NOUT + col] = f2bf(v);
        }
}

template<int NT>
__device__ inline void store_c_swz_f32(float* Bt, f32x4* acc, int lane)
{
    int r0 = (lane >> 4) << 2;
    int c  = lane & 15;
    #pragma unroll
    for (int nt = 0; nt < NT; ++nt)
        #pragma unroll
        for (int i = 0; i < 4; ++i) {
            int row = r0 + i;
            int col = (nt * 16 + c) ^ ((row & 7) << 2);
            Bt[row * 64 + col] = acc[nt][i];
        }
}

// swizzled LDS tile -> global, full 16B/lane writes, conflict-free reads
template<int NOUT>
__device__ inline void copy_swz16(const u16* Bt, u16* __restrict__ Y,
                                  int rowbase, int nN, int lane)
{
    constexpr int CPR   = NOUT / 8;            // 16B chunks per row
    constexpr int ITERS = 16 * CPR / 64;
    #pragma unroll
    for (int it = 0; it < ITERS; ++it) {
        int flat = it * 64 + lane;
        int row  = flat / CPR;
        int j    = flat % CPR;
        int pcol = (j * 8) ^ ((row & 7) << 3); // physical loc of logical chunk j
        int gr = rowbase + row;
        if (gr < nN)
            *reinterpret_cast<int4*>(Y + (size_t)gr * NOUT + j * 8) =
                *reinterpret_cast<const int4*>(Bt + row * NOUT + pcol);
    }
}

__device__ inline void copy_swz_f32(const float* Bt, float* __restrict__ Y,
                                    int rowbase, int nN, int lane)
{
    // 16 rows x 64 f32, 16 chunks(16B)/row, 4 iters
    #pragma unroll
    for (int it = 0; it < 4; ++it) {
        int flat = it * 64 + lane;
        int row  = flat >> 4;
        int j    = flat & 15;
        int pcol = (j * 4) ^ ((row & 7) << 2);
        int gr = rowbase + row;
        if (gr < nN)
            *reinterpret_cast<int4*>(Y + (size_t)gr * 64 + j * 4) =
                *reinterpret_cast<const int4*>(Bt + row * 64 + pcol);
    }
}

// ---------------------------------------------------------------------------
// front body: t1 = x@W1 ; s_c = relu(x@Wm1+bm1)@Wm2+bm2 — stores via swz LDS
// ---------------------------------------------------------------------------
template<int SA>
__device__ inline void front_body(
    const float* __restrict__ X, const u16* __restrict__ W1f,
    const u16* __restrict__ Wm1f, const float* __restrict__ bm1,
    const u16* __restrict__ Wm2f, const float* __restrict__ bm2,
    u16* __restrict__ T1, u16* __restrict__ Sc, int nN,
    u16* At, u16* Bt, int rowbase, int lane)
{
    stage_cvt_tile<SA>(At, X, rowbase, nN, lane);
    {
        f32x4 acc[8];
        init_acc<8>(acc, nullptr, lane);
        mfma_pass<4, 8, SA>(At, W1f, lane, acc);
        store_c_swz<8, 128, false>(Bt, acc, lane);
        copy_swz16<128>(Bt, T1, rowbase, nN, lane);
    }
    {
        f32x4 acc[8];
        init_acc<8>(acc, bm1, lane);
        mfma_pass<4, 8, SA>(At, Wm1f, lane, acc);
        store_c_swz<8, 128, true>(Bt, acc, lane);    // s1 (relu)
    }
    {
        f32x4 acc[4];
        init_acc<4>(acc, bm2, lane);
        mfma_pass_swz<4, 4, 128>(Bt, Wm2f, lane, acc);
        store_c_swz<4, 64, false>(Bt, acc, lane);    // overwrite after reads
        copy_swz16<64>(Bt, Sc, rowbase, nN, lane);
    }
}

// K4: fused front (blocks [0,nFront)) + level-1 place (blocks [nFront,...)).
__global__ __launch_bounds__(256) void front_place(
    const float* __restrict__ X,
    const u16* __restrict__ W1f,
    const u16* __restrict__ Wm1f, const float* __restrict__ bm1,
    const u16* __restrict__ Wm2f, const float* __restrict__ bm2,
    u16* __restrict__ T1, u16* __restrict__ Sc, int nN, int nFront,
    const int* __restrict__ esrc, const int* __restrict__ edst,
    const float* __restrict__ ew, const int* __restrict__ C,
    const int* __restrict__ boff, int2* __restrict__ pl1,
    int E, int NBUK, int CE)
{
    constexpr int SA = 136;
    __shared__ __align__(16) u16 As[4 * 16 * SA];
    __shared__ __align__(16) u16 Bs[4 * 16 * 128];
    __shared__ int cur[512];
    int tid = threadIdx.x;

    if (blockIdx.x >= nFront) {
        // ---- place role ----
        int blk = blockIdx.x - nFront;
        for (int i = tid; i < NBUK; i += 256) {
            int f = i * NBLK + blk;
            cur[i] = C[f] + boff[f >> 10];
        }
        __syncthreads();
        int e0 = blk * CE, e1 = min(E, e0 + CE);
        for (int e = e0 + tid; e < e1; e += 256) {
            int d  = __builtin_nontemporal_load(edst + e);
            int s  = __builtin_nontemporal_load(esrc + e);
            float ww = __builtin_nontemporal_load(ew + e);
            int pos = atomicAdd(&cur[d >> BSH], 1);
            pl1[pos] = make_int2(s | ((d & (BROWS - 1)) << 20), __float_as_int(ww));
        }
        return;
    }

    // ---- front role (wave-private tiles, no barriers) ----
    int w = tid >> 6, lane = tid & 63;
    int rowbase = blockIdx.x * 64 + w * 16;
    front_body<SA>(X, W1f, Wm1f, bm1, Wm2f, bm2, T1, Sc, nN,
                   As + w * 16 * SA, Bs + w * 16 * 128, rowbase, lane);
}

// fallback front
__global__ __launch_bounds__(256) void front_kernel(
    const float* __restrict__ X,
    const u16* __restrict__ W1f,
    const u16* __restrict__ Wm1f, const float* __restrict__ bm1,
    const u16* __restrict__ Wm2f, const float* __restrict__ bm2,
    u16* __restrict__ T1, u16* __restrict__ Sc, int nN)
{
    constexpr int SA = 136;
    __shared__ __align__(16) u16 As[4 * 16 * SA];
    __shared__ __align__(16) u16 Bs[4 * 16 * 128];
    int tid = threadIdx.x, w = tid >> 6, lane = tid & 63;
    int rowbase = blockIdx.x * 64 + w * 16;
    front_body<SA>(X, W1f, Wm1f, bm1, Wm2f, bm2, T1, Sc, nN,
                   As + w * 16 * SA, Bs + w * 16 * 128, rowbase, lane);
}

// ---------------------------------------------------------------------------
// K5: level-2 row-sort, 512 threads, LDS-staged segment (single pl1 read).
// ---------------------------------------------------------------------------
__global__ __launch_bounds__(512) void sort_bucket2(
    const int2* __restrict__ pl1, const int* __restrict__ C,
    const int* __restrict__ boff, int2* __restrict__ pairs,
    int* __restrict__ rowptr, int E, int nN, int NBUK)
{
    __shared__ int2 sseg[SCAP];
    __shared__ int hist[BROWS], s[BROWS], cur[BROWS];
    int b = blockIdx.x, tid = threadIdx.x;
    int f0 = b * NBLK;
    int segb = C[f0] + boff[f0 >> 10];
    int sege;
    if (b + 1 < NBUK) {
        int f1 = (b + 1) * NBLK;
        sege = C[f1] + boff[f1 >> 10];
    } else sege = E;
    int seg = sege - segb;
    int stg = min(seg, SCAP);

    for (int i = tid; i < stg; i += 512) sseg[i] = pl1[segb + i];
    if (tid < BROWS) hist[tid] = 0;
    __syncthreads();
    for (int i = tid; i < stg; i += 512)
        atomicAdd(&hist[(u32)sseg[i].x >> 20], 1);
    for (int i = segb + stg + tid; i < sege; i += 512)
        atomicAdd(&hist[(u32)pl1[i].x >> 20], 1);
    __syncthreads();
    if (tid < BROWS) s[tid] = hist[tid];
    __syncthreads();
    for (int off = 1; off < BROWS; off <<= 1) {
        int t = 0;
        if (tid < BROWS && tid >= off) t = s[tid - off];
        __syncthreads();
        if (tid < BROWS) s[tid] += t;
        __syncthreads();
    }
    if (tid < BROWS) {
        int excl = segb + s[tid] - hist[tid];
        cur[tid] = excl;
        int row = b * BROWS + tid;
        if (row < nN) rowptr[row] = excl;
    }
    if (b == 0 && tid == 0) rowptr[nN] = E;
    __syncthreads();
    for (int i = tid; i < stg; i += 512) {
        int2 pr = sseg[i];
        int pos = atomicAdd(&cur[(u32)pr.x >> 20], 1);
        pairs[pos] = make_int2(pr.x & 0xFFFFF, pr.y);
    }
    for (int i = segb + stg + tid; i < sege; i += 512) {
        int2 pr = pl1[i];
        int pos = atomicAdd(&cur[(u32)pr.x >> 20], 1);
        pairs[pos] = make_int2(pr.x & 0xFFFFF, pr.y);
    }
}

// ---------------- fallback CSR build (large nN/E) --------------------------
__global__ __launch_bounds__(256) void rank_kernel(
    const int* __restrict__ dst, int* __restrict__ cnt,
    int* __restrict__ rank, int E)
{
    int i = blockIdx.x * blockDim.x + threadIdx.x;
    int ns = gridDim.x * blockDim.x;
    for (int e = i; e < E; e += ns) {
        int d = __builtin_nontemporal_load(dst + e);
        rank[e] = atomicAdd(&cnt[d], 1);
    }
}

__global__ __launch_bounds__(256) void scan3_fb(
    const int* __restrict__ data, const int* __restrict__ boff,
    int* __restrict__ rowptr, int n, int E)
{
    int i = blockIdx.x * blockDim.x + threadIdx.x;
    if (i < n) rowptr[i] = data[i] + boff[i >> 10];
    if (i == 0) rowptr[n] = E;
}

__global__ __launch_bounds__(256) void place_oct(
    const int* __restrict__ src, const int* __restrict__ dst,
    const float* __restrict__ w, const int* __restrict__ rank,
    const int* __restrict__ rowptr, int2* __restrict__ pairs, int E, int nN)
{
    int oct  = blockIdx.x & 7;
    int grp  = blockIdx.x >> 3;
    int ngrp = gridDim.x >> 3;
    int chunk = (nN + 7) / 8;
    int b0 = oct * chunk;
    int b1 = min(nN, b0 + chunk);
    int i  = grp * blockDim.x + threadIdx.x;
    int ns = ngrp * blockDim.x;
    for (int e = i; e < E; e += ns) {
        int d = __builtin_nontemporal_load(dst + e);
        if (d >= b0 && d < b1) {
            int pos  = rowptr[d] + __builtin_nontemporal_load(rank + e);
            int s    = __builtin_nontemporal_load(src + e);
            float ww = __builtin_nontemporal_load(w + e);
            pairs[pos] = make_int2(s, __float_as_int(ww));
        }
    }
}

// ---------------------------------------------------------------------------
template<int K, int NOUT, bool RELU>
__global__ __launch_bounds__(256) void gemm_mfma(
    const u16* __restrict__ Xb, const u16* __restrict__ Wf,
    const float* __restrict__ bias, u16* __restrict__ Y, int nN)
{
    constexpr int SA = K + 8;
    __shared__ __align__(16) u16 As[4 * 16 * SA];
    __shared__ __align__(16) u16 Bs[4 * 16 * NOUT];
    int tid = threadIdx.x, w = tid >> 6, lane = tid & 63;
    int rowbase = blockIdx.x * 64 + w * 16;
    u16* At = As + w * 16 * SA;
    u16* Bt = Bs + w * 16 * NOUT;
    stage_tile<K, SA>(At, Xb, rowbase, nN, lane, 0);
    f32x4 acc[NOUT / 16];
    init_acc<NOUT / 16>(acc, bias, lane);
    mfma_pass<K / 32, NOUT / 16, SA>(At, Wf, lane, acc);
    store_c_swz<NOUT / 16, NOUT, RELU>(Bt, acc, lane);
    copy_swz16<NOUT>(Bt, Y, rowbase, nN, lane);
}

// tail: out = relu([s_c|conv1|conv2]@Wh1+bh1) @ Wh2 + bh2  -> fp32 (swz LDS)
__global__ __launch_bounds__(256) void tail_mfma_kernel(
    const u16* __restrict__ Sc, const u16* __restrict__ C1, const u16* __restrict__ C2,
    const u16* __restrict__ Wh1f, const float* __restrict__ bh1,
    const u16* __restrict__ Wh2f, const float* __restrict__ bh2,
    float* __restrict__ out, int nN)
{
    constexpr int SA1 = 264;
    __shared__ __align__(16) u16 As[4 * 16 * SA1];
    __shared__ __align__(16) u16 Bs[4 * 16 * 128];   // 4KB/wave; f32 view 16x64
    int tid = threadIdx.x, w = tid >> 6, lane = tid & 63;
    int rowbase = blockIdx.x * 64 + w * 16;
    u16* At = As + w * 16 * SA1;
    u16* Bt = Bs + w * 16 * 128;
    stage_tile<64,  SA1>(At, Sc, rowbase, nN, lane, 0);
    stage_tile<128, SA1>(At, C1, rowbase, nN, lane, 64);
    stage_tile<64,  SA1>(At, C2, rowbase, nN, lane, 192);
    {
        f32x4 acc[8];
        init_acc<8>(acc, bh1, lane);
        mfma_pass<8, 8, SA1>(At, Wh1f, lane, acc);
        store_c_swz<8, 128, true>(Bt, acc, lane);
    }
    {
        f32x4 acc[4];
        init_acc<4>(acc, bh2, lane);
        mfma_pass_swz<4, 4, 128>(Bt, Wh2f, lane, acc);
        float* Btf = reinterpret_cast<float*>(Bt);
        store_c_swz_f32<4>(Btf, acc, lane);          // overwrite after reads
        copy_swz_f32(Btf, out, rowbase, nN, lane);
    }
}

// ---------------------------------------------------------------------------
// CSR SpMM gather (packed pairs), bf16 x, fp32 accum
// ---------------------------------------------------------------------------
template<bool RELU>
__global__ __launch_bounds__(256) void spmm128_bf(
    const int* __restrict__ rowptr, const int2* __restrict__ pairs,
    const u16* __restrict__ x, u16* __restrict__ y, int nN)
{
    int lane = threadIdx.x & 63;
    int row  = (blockIdx.x * blockDim.x + threadIdx.x) >> 6;
    if (row >= nN) return;
    int rs = rowptr[row], re = rowptr[row + 1];
    float a0 = 0.f, a1 = 0.f;
    for (int base = rs; base < re; base += 64) {
        int e = base + lane;
        int2 pr = make_int2(0, 0);
        if (e < re) pr = pairs[e];
        int cnt = min(64, re - base);
        int j = 0;
        for (; j + 4 <= cnt; j += 4) {
            int   s0 = __shfl(pr.x, j+0), s1 = __shfl(pr.x, j+1),
                  s2 = __shfl(pr.x, j+2), s3 = __shfl(pr.x, j+3);
            float w0 = __int_as_float(__shfl(pr.y, j+0)),
                  w1 = __int_as_float(__shfl(pr.y, j+1)),
                  w2 = __int_as_float(__shfl(pr.y, j+2)),
                  w3 = __int_as_float(__shfl(pr.y, j+3));
            u32 u0 = *reinterpret_cast<const u32*>(x + (size_t)s0 * 128 + lane * 2);
            u32 u1 = *reinterpret_cast<const u32*>(x + (size_t)s1 * 128 + lane * 2);
            u32 u2 = *reinterpret_cast<const u32*>(x + (size_t)s2 * 128 + lane * 2);
            u32 u3 = *reinterpret_cast<const u32*>(x + (size_t)s3 * 128 + lane * 2);
            a0 += w0 * bflo(u0); a1 += w0 * bfhi(u0);
            a0 += w1 * bflo(u1); a1 += w1 * bfhi(u1);
            a0 += w2 * bflo(u2); a1 += w2 * bfhi(u2);
            a0 += w3 * bflo(u3); a1 += w3 * bfhi(u3);
        }
        for (; j < cnt; ++j) {
            int   s = __shfl(pr.x, j);
            float ww = __int_as_float(__shfl(pr.y, j));
            u32 u = *reinterpret_cast<const u32*>(x + (size_t)s * 128 + lane * 2);
            a0 += ww * bflo(u); a1 += ww * bfhi(u);
        }
    }
    if (RELU) { a0 = fmaxf(a0, 0.f); a1 = fmaxf(a1, 0.f); }
    u32 o = (u32)f2bf(a0) | ((u32)f2bf(a1) << 16);
    *reinterpret_cast<u32*>(y + (size_t)row * 128 + lane * 2) = o;
}

__global__ __launch_bounds__(256) void spmm64_bf(
    const int* __restrict__ rowptr, const int2* __restrict__ pairs,
    const u16* __restrict__ x, u16* __restrict__ y, int nN)
{
    int lane = threadIdx.x & 63;
    int wp   = (blockIdx.x * blockDim.x + threadIdx.x) >> 6;
    int sub  = lane >> 5, sl = lane & 31;
    int row  = wp * 2 + sub;
    if (wp * 2 >= nN) return;
    bool live = row < nN;
    int rs = live ? rowptr[row] : 0;
    int re = live ? rowptr[row + 1] : 0;
    float a0 = 0.f, a1 = 0.f;
    for (int base = rs; base < re; base += 32) {
        int e = base + sl;
        int2 pr = make_int2(0, 0);
        if (e < re) pr = pairs[e];
        int cnt = min(32, re - base);
        int j = 0;
        for (; j + 4 <= cnt; j += 4) {
            int   s0 = __shfl(pr.x, j+0, 32), s1 = __shfl(pr.x, j+1, 32),
                  s2 = __shfl(pr.x, j+2, 32), s3 = __shfl(pr.x, j+3, 32);
            float w0 = __int_as_float(__shfl(pr.y, j+0, 32)),
                  w1 = __int_as_float(__shfl(pr.y, j+1, 32)),
                  w2 = __int_as_float(__shfl(pr.y, j+2, 32)),
                  w3 = __int_as_float(__shfl(pr.y, j+3, 32));
            u32 u0 = *reinterpret_cast<const u32*>(x + (size_t)s0 * 64 + sl * 2);
            u32 u1 = *reinterpret_cast<const u32*>(x + (size_t)s1 * 64 + sl * 2);
            u32 u2 = *reinterpret_cast<const u32*>(x + (size_t)s2 * 64 + sl * 2);
            u32 u3 = *reinterpret_cast<const u32*>(x + (size_t)s3 * 64 + sl * 2);
            a0 += w0 * bflo(u0); a1 += w0 * bfhi(u0);
            a0 += w1 * bflo(u1); a1 += w1 * bfhi(u1);
            a0 += w2 * bflo(u2); a1 += w2 * bfhi(u2);
            a0 += w3 * bflo(u3); a1 += w3 * bfhi(u3);
        }
        for (; j < cnt; ++j) {
            int   s = __shfl(pr.x, j, 32);
            float ww = __int_as_float(__shfl(pr.y, j, 32));
            u32 u = *reinterpret_cast<const u32*>(x + (size_t)s * 64 + sl * 2);
            a0 += ww * bflo(u); a1 += ww * bfhi(u);
        }
    }
    if (live) {
        u32 o = (u32)f2bf(a0) | ((u32)f2bf(a1) << 16);
        *reinterpret_cast<u32*>(y + (size_t)row * 64 + sl * 2) = o;
    }
}

// ===========================================================================
extern "C" void kernel_launch(void* const* d_in, const int* in_sizes, int n_in,
                              void* d_out, int out_size, void* d_ws, size_t ws_size,
                              hipStream_t stream)
{
    const float* features = (const float*)d_in[0];
    const int*   esrc     = (const int*)d_in[1];
    const int*   edst     = (const int*)d_in[2];
    const float* ew       = (const float*)d_in[3];
    const float* W1  = (const float*)d_in[4];
    const float* W2  = (const float*)d_in[5];
    const float* Wm1 = (const float*)d_in[6];
    const float* bm1 = (const float*)d_in[7];
    const float* Wm2 = (const float*)d_in[8];
    const float* bm2 = (const float*)d_in[9];
    const float* Wh1 = (const float*)d_in[10];
    const float* bh1 = (const float*)d_in[11];
    const float* Wh2 = (const float*)d_in[12];
    const float* bh2 = (const float*)d_in[13];

    int nN = in_sizes[0] / D;   // 50000
    int E  = in_sizes[1];       // 1.6M
    float* out = (float*)d_out;

    // ---- workspace bump allocation ----
    char* base = (char*)d_ws;
    size_t off = 0;
    auto alloc = [&](size_t bytes) -> char* {
        char* p = base + off;
        off += (bytes + 255) & ~(size_t)255;
        return p;
    };
    u16*  conv2b = (u16*)alloc((size_t)nN * 64 * 2);   // C aliases this pre-spmm64
    u16*  t1b    = (u16*)alloc((size_t)nN * 128 * 2);  // t1b, later t2b
    u16*  conv1b = (u16*)alloc((size_t)nN * 128 * 2);  // pl1/rank alias pre-spmm128
    u16*  s_cb   = (u16*)alloc((size_t)nN * 64 * 2);
    int2* pairs  = (int2*)alloc((size_t)E * 8);
    int* rowptr  = (int*)alloc(((size_t)nN + 1) * 4);
    int* tmp     = (int*)alloc((size_t)nN * 4);        // fallback counts
    int* bsum    = (int*)alloc(4096 * 4);
    int* boff    = (int*)alloc(4096 * 4);
    u16* W1f  = (u16*)alloc(4 * 8 * 64 * 8 * 2);
    u16* Wm1f = (u16*)alloc(4 * 8 * 64 * 8 * 2);
    u16* W2f  = (u16*)alloc(4 * 4 * 64 * 8 * 2);
    u16* Wm2f = (u16*)alloc(4 * 4 * 64 * 8 * 2);
    u16* Wh2f = (u16*)alloc(4 * 4 * 64 * 8 * 2);
    u16* Wh1f = (u16*)alloc(8 * 8 * 64 * 8 * 2);
    u16* t2b = t1b;                  // [N,64] bf16, t1 dead after conv1 spmm
    int2* pl1 = (int2*)conv1b;       // level-1 pairs, dead before conv1 write
    int*  C   = (int*)conv2b;        // [NBUK*NBLK], dead before spmm64 writes conv2b

    int gGemm   = (nN + 63) / 64;
    int gSpmm1  = (nN + 3) / 4;
    int gSpmm64 = ((nN + 1) / 2 + 3) / 4;

    int NBUK = (nN + BROWS - 1) >> BSH;
    bool mainPath = (NBUK <= 512) && (nN < (1 << 20)) &&
                    ((size_t)E * 8 <= (size_t)nN * 256) &&
                    ((size_t)NBUK * NBLK * 4 <= (size_t)nN * 128);
    if (mainPath) {
        int CE = (E + NBLK - 1) / NBLK;
        int n2 = NBUK * NBLK;
        int nb1 = (n2 + 1023) / 1024;
        // K1: repack + hist
        fused_prep<<<REPACK_BLKS + NBLK, 256, 0, stream>>>(
            W1, W1f, Wm1, Wm1f, W2, W2f, Wm2, Wm2f, Wh2, Wh2f, Wh1, Wh1f,
            edst, C, E, NBUK, CE);
        // K2/K3: scan
        scan1_kernel<<<nb1, 1024, 0, stream>>>(C, bsum, n2);
        scan_carry<<<1, 1024, 0, stream>>>(bsum, boff, nb1);
        // K4: front + place (boff added inline)
        front_place<<<gGemm + NBLK, 256, 0, stream>>>(
            features, W1f, Wm1f, bm1, Wm2f, bm2, t1b, s_cb, nN, gGemm,
            esrc, edst, ew, C, boff, pl1, E, NBUK, CE);
        // K5: row-sort buckets
        sort_bucket2<<<NBUK, 512, 0, stream>>>(pl1, C, boff, pairs, rowptr, E, nN, NBUK);
    } else {
        // fallback: rank/place + separate front
        int* rank = (int*)conv1b;
        fused_prep<<<REPACK_BLKS, 256, 0, stream>>>(
            W1, W1f, Wm1, Wm1f, W2, W2f, Wm2, Wm2f, Wh2, Wh2f, Wh1, Wh1f,
            edst, C, 0, 1, 1);   // repack-only (hist blocks absent)
        hipMemsetAsync(tmp, 0, (size_t)nN * 4, stream);
        rank_kernel<<<1024, 256, 0, stream>>>(edst, tmp, rank, E);
        int nb1 = (nN + 1023) / 1024;
        scan1_kernel<<<nb1, 1024, 0, stream>>>(tmp, bsum, nN);
        scan_carry<<<1, 1024, 0, stream>>>(bsum, boff, nb1);
        scan3_fb<<<(nN + 255) / 256, 256, 0, stream>>>(tmp, boff, rowptr, nN, E);
        place_oct<<<2048, 256, 0, stream>>>(esrc, edst, ew, rank, rowptr, pairs, E, nN);
        front_kernel<<<gGemm, 256, 0, stream>>>(features, W1f, Wm1f, bm1, Wm2f, bm2,
                                                t1b, s_cb, nN);
    }

    // conv1 = relu(A . t1)
    spmm128_bf<true><<<gSpmm1, 256, 0, stream>>>(rowptr, pairs, t1b, conv1b, nN);
    // t2 = conv1 @ W2
    gemm_mfma<128, 64, false><<<gGemm, 256, 0, stream>>>(conv1b, W2f, nullptr, t2b, nN);
    // conv2 = A . t2
    spmm64_bf<<<gSpmm64, 256, 0, stream>>>(rowptr, pairs, t2b, conv2b, nN);
    // out = relu([s_c|conv1|conv2]@Wh1+bh1)@Wh2+bh2
    tail_mfma_kernel<<<gGemm, 256, 0, stream>>>(s_cb, conv1b, conv2b,
                                                Wh1f, bh1, Wh2f, bh2, out, nN);
}

// Round 12
// 187.531 us; speedup vs baseline: 1.1838x; 1.1838x over previous
//
#include <hip/hip_runtime.h>

typedef float  f32x4 __attribute__((ext_vector_type(4)));
typedef short  s16x8 __attribute__((ext_vector_type(8)));
typedef unsigned short u16;
typedef unsigned int   u32;

constexpr int D    = 128;
constexpr int DOUT = 64;
constexpr int NBLK = 256;   // edge chunks for level-1 hist/place
constexpr int BSH  = 7;     // 128 rows per bucket
constexpr int BROWS = 128;
constexpr int SCAP = 5120;  // staged edges per bucket in sort (40KB LDS)
constexpr int REPACK_BLKS = 44; // ceil(11264/256)

// ---------------------------------------------------------------------------
__device__ inline u16 f2bf(float f) {
    u32 x = __float_as_uint(f);
    u32 r = (x + 0x7fffu + ((x >> 16) & 1u)) >> 16;
    return (u16)r;
}
__device__ inline float bflo(u32 u) { return __uint_as_float(u << 16); }
__device__ inline float bfhi(u32 u) { return __uint_as_float(u & 0xffff0000u); }

// ---------------------------------------------------------------------------
// Weight repack body (6 weights -> MFMA B-fragment-linear bf16), t in [0,11264)
// ---------------------------------------------------------------------------
__device__ inline void repack_body(int t,
    const float* __restrict__ W1,  u16* __restrict__ W1f,
    const float* __restrict__ Wm1, u16* __restrict__ Wm1f,
    const float* __restrict__ W2,  u16* __restrict__ W2f,
    const float* __restrict__ Wm2, u16* __restrict__ Wm2f,
    const float* __restrict__ Wh2, u16* __restrict__ Wh2f,
    const float* __restrict__ Wh1, u16* __restrict__ Wh1f)
{
    const float* W; u16* Wf; int NT, NOUT, base;
    if      (t < 2048)  { W = W1;  Wf = W1f;  NT = 8; NOUT = 128; base = 0; }
    else if (t < 4096)  { W = Wm1; Wf = Wm1f; NT = 8; NOUT = 128; base = 2048; }
    else if (t < 5120)  { W = W2;  Wf = W2f;  NT = 4; NOUT = 64;  base = 4096; }
    else if (t < 6144)  { W = Wm2; Wf = Wm2f; NT = 4; NOUT = 64;  base = 5120; }
    else if (t < 7168)  { W = Wh2; Wf = Wh2f; NT = 4; NOUT = 64;  base = 6144; }
    else                { W = Wh1; Wf = Wh1f; NT = 8; NOUT = 128; base = 7168; }
    int lt   = t - base;
    int kk   = lt / (NT * 64);
    int rem  = lt % (NT * 64);
    int nt   = rem / 64;
    int lane = rem % 64;
    int k0 = kk * 32 + ((lane >> 4) << 3);
    int c  = nt * 16 + (lane & 15);
    #pragma unroll
    for (int j = 0; j < 8; ++j)
        Wf[(size_t)lt * 8 + j] = f2bf(W[(size_t)(k0 + j) * NOUT + c]);
}

// K1: fused repack (blocks [0,44)) + level-1 bucket histogram (blocks [44,...))
__global__ __launch_bounds__(256) void fused_prep(
    const float* __restrict__ W1,  u16* __restrict__ W1f,
    const float* __restrict__ Wm1, u16* __restrict__ Wm1f,
    const float* __restrict__ W2,  u16* __restrict__ W2f,
    const float* __restrict__ Wm2, u16* __restrict__ Wm2f,
    const float* __restrict__ Wh2, u16* __restrict__ Wh2f,
    const float* __restrict__ Wh1, u16* __restrict__ Wh1f,
    const int* __restrict__ dst, int* __restrict__ C, int E, int NBUK, int CE)
{
    __shared__ int h[512];
    if (blockIdx.x < REPACK_BLKS) {
        int t = blockIdx.x * 256 + threadIdx.x;
        if (t < 11264)
            repack_body(t, W1, W1f, Wm1, Wm1f, W2, W2f, Wm2, Wm2f, Wh2, Wh2f, Wh1, Wh1f);
        return;
    }
    int blk = blockIdx.x - REPACK_BLKS;
    for (int i = threadIdx.x; i < NBUK; i += 256) h[i] = 0;
    __syncthreads();
    int e0 = blk * CE, e1 = min(E, e0 + CE);
    for (int e = e0 + threadIdx.x; e < e1; e += 256) {
        int d = __builtin_nontemporal_load(dst + e);
        atomicAdd(&h[d >> BSH], 1);
    }
    __syncthreads();
    for (int i = threadIdx.x; i < NBUK; i += 256)
        C[i * NBLK + blk] = h[i];
}

// ---------------------------------------------------------------------------
__global__ __launch_bounds__(1024) void scan1_kernel(
    int* __restrict__ data, int* __restrict__ bsum, int n)
{
    __shared__ int sm[1024];
    int tid = threadIdx.x;
    int i = blockIdx.x * 1024 + tid;
    int v = (i < n) ? data[i] : 0;
    sm[tid] = v;
    __syncthreads();
    #pragma unroll
    for (int off = 1; off < 1024; off <<= 1) {
        int t = (tid >= off) ? sm[tid - off] : 0;
        __syncthreads();
        sm[tid] += t;
        __syncthreads();
    }
    if (i < n) data[i] = sm[tid] - v;   // exclusive within chunk
    if (tid == 1023) bsum[blockIdx.x] = sm[1023];
}

__global__ __launch_bounds__(1024) void scan_carry(
    const int* __restrict__ in, int* __restrict__ outExc, int n)
{
    __shared__ int sm[1024];
    __shared__ int s_carry;
    int tid = threadIdx.x;
    if (tid == 0) s_carry = 0;
    __syncthreads();
    for (int base = 0; base < n; base += 1024) {
        int i = base + tid;
        int v = (i < n) ? in[i] : 0;
        sm[tid] = v;
        __syncthreads();
        for (int off = 1; off < 1024; off <<= 1) {
            int t = (tid >= off) ? sm[tid - off] : 0;
            __syncthreads();
            sm[tid] += t;
            __syncthreads();
        }
        int carry = s_carry;
        if (i < n) outExc[i] = carry + sm[tid] - v;
        __syncthreads();
        if (tid == 1023) s_carry = carry + sm[1023];
        __syncthreads();
    }
}

// ---------------------------------------------------------------------------
// MFMA building blocks
// ---------------------------------------------------------------------------
template<int WIDTH, int SA>
__device__ inline void stage_tile(u16* Atile, const u16* __restrict__ src,
                                  int rowbase, int nN, int lane, int colOff)
{
    constexpr int BPR   = WIDTH * 2;
    constexpr int ITERS = (16 * BPR) / 1024;
    #pragma unroll
    for (int it = 0; it < ITERS; ++it) {
        int flat = it * 1024 + lane * 16;
        int row  = flat / BPR;
        int colS = (flat % BPR) >> 1;
        int4 v = make_int4(0, 0, 0, 0);
        int gr = rowbase + row;
        if (gr < nN)
            v = *reinterpret_cast<const int4*>(src + (size_t)gr * WIDTH + colS);
        *reinterpret_cast<int4*>(Atile + row * SA + colOff + colS) = v;
    }
}

// stage 16x128 fp32 tile -> bf16 LDS (fused convert, nt source)
template<int SA>
__device__ inline void stage_cvt_tile(u16* Atile, const float* __restrict__ src,
                                      int rowbase, int nN, int lane)
{
    #pragma unroll
    for (int it = 0; it < 8; ++it) {
        int flat = it * 1024 + lane * 16;
        int row  = flat >> 9;
        int c4   = (flat & 511) >> 2;
        f32x4 v = (f32x4){0.f, 0.f, 0.f, 0.f};
        int gr = rowbase + row;
        if (gr < nN)
            v = __builtin_nontemporal_load(
                    reinterpret_cast<const f32x4*>(src + (size_t)gr * 128 + c4));
        u32 p0 = (u32)f2bf(v.x) | ((u32)f2bf(v.y) << 16);
        u32 p1 = (u32)f2bf(v.z) | ((u32)f2bf(v.w) << 16);
        *reinterpret_cast<u32*>(Atile + row * SA + c4)     = p0;
        *reinterpret_cast<u32*>(Atile + row * SA + c4 + 2) = p1;
    }
}

template<int NT>
__device__ inline void init_acc(f32x4* acc, const float* __restrict__ bias, int lane)
{
    #pragma unroll
    for (int nt = 0; nt < NT; ++nt) {
        float bv = bias ? bias[nt * 16 + (lane & 15)] : 0.f;
        acc[nt] = (f32x4){bv, bv, bv, bv};
    }
}

template<int KK, int NT, int SA>
__device__ inline void mfma_pass(const u16* Atile, const u16* __restrict__ Wf,
                                 int lane, f32x4* acc)
{
    const u16* ap = Atile + (lane & 15) * SA + ((lane >> 4) << 3);
    #pragma unroll
    for (int kk = 0; kk < KK; ++kk) {
        s16x8 a = *reinterpret_cast<const s16x8*>(ap + kk * 32);
        #pragma unroll
        for (int nt = 0; nt < NT; ++nt) {
            s16x8 b = *reinterpret_cast<const s16x8*>(Wf + ((size_t)(kk * NT + nt) * 64 + lane) * 8);
            acc[nt] = __builtin_amdgcn_mfma_f32_16x16x32_bf16(a, b, acc[nt], 0, 0, 0);
        }
    }
}

template<int NT, int SA, bool RELU>
__device__ inline void store_c_lds(u16* Btile, f32x4* acc, int lane)
{
    int r0 = (lane >> 4) << 2;
    int c  = lane & 15;
    #pragma unroll
    for (int nt = 0; nt < NT; ++nt)
        #pragma unroll
        for (int i = 0; i < 4; ++i) {
            float v = acc[nt][i];
            if (RELU) v = fmaxf(v, 0.f);
            Btile[(r0 + i) * SA + nt * 16 + c] = f2bf(v);
        }
}

template<int NT, int NOUT, bool RELU, bool OBF16>
__device__ inline void store_c_global(void* Y, f32x4* acc, int rowbase, int nN, int lane)
{
    int r0 = rowbase + ((lane >> 4) << 2);
    int c  = lane & 15;
    #pragma unroll
    for (int nt = 0; nt < NT; ++nt) {
        int col = nt * 16 + c;
        #pragma unroll
        for (int i = 0; i < 4; ++i) {
            int r = r0 + i;
            if (r < nN) {
                float v = acc[nt][i];
                if (RELU) v = fmaxf(v, 0.f);
                if (OBF16) ((u16*)Y)[(size_t)r * NOUT + col] = f2bf(v);
                else       ((float*)Y)[(size_t)r * NOUT + col] = v;
            }
        }
    }
}

// ---------------------------------------------------------------------------
// K4: fused front (blocks [0,nFront)) + level-1 place (blocks [nFront,...)).
// front: t1 = x@W1 ; s_c = relu(x@Wm1+bm1)@Wm2+bm2  (fp32->bf16 in staging)
// place: pl1[pos] = (src | dlocal<<20, w) at pos = scanned C (+boff inline)
// ---------------------------------------------------------------------------
__global__ __launch_bounds__(256) void front_place(
    const float* __restrict__ X,
    const u16* __restrict__ W1f,
    const u16* __restrict__ Wm1f, const float* __restrict__ bm1,
    const u16* __restrict__ Wm2f, const float* __restrict__ bm2,
    u16* __restrict__ T1, u16* __restrict__ Sc, int nN, int nFront,
    const int* __restrict__ esrc, const int* __restrict__ edst,
    const float* __restrict__ ew, const int* __restrict__ C,
    const int* __restrict__ boff, int2* __restrict__ pl1,
    int E, int NBUK, int CE)
{
    constexpr int SA = 136;
    __shared__ __align__(16) u16 As[4 * 16 * SA];
    __shared__ __align__(16) u16 Bs[4 * 16 * SA];
    __shared__ int cur[512];
    int tid = threadIdx.x;

    if (blockIdx.x >= nFront) {
        // ---- place role ----
        int blk = blockIdx.x - nFront;
        for (int i = tid; i < NBUK; i += 256) {
            int f = i * NBLK + blk;
            cur[i] = C[f] + boff[f >> 10];
        }
        __syncthreads();
        int e0 = blk * CE, e1 = min(E, e0 + CE);
        for (int e = e0 + tid; e < e1; e += 256) {
            int d  = __builtin_nontemporal_load(edst + e);
            int s  = __builtin_nontemporal_load(esrc + e);
            float ww = __builtin_nontemporal_load(ew + e);
            int pos = atomicAdd(&cur[d >> BSH], 1);
            pl1[pos] = make_int2(s | ((d & (BROWS - 1)) << 20), __float_as_int(ww));
        }
        return;
    }

    // ---- front role ----
    int w = tid >> 6, lane = tid & 63;
    int rowbase = blockIdx.x * 64 + w * 16;
    u16* At = As + w * 16 * SA;
    u16* Bt = Bs + w * 16 * SA;
    stage_cvt_tile<SA>(At, X, rowbase, nN, lane);
    {
        f32x4 acc[8];
        init_acc<8>(acc, nullptr, lane);
        mfma_pass<4, 8, SA>(At, W1f, lane, acc);
        store_c_global<8, 128, false, true>(T1, acc, rowbase, nN, lane);
    }
    {
        f32x4 acc[8];
        init_acc<8>(acc, bm1, lane);
        mfma_pass<4, 8, SA>(At, Wm1f, lane, acc);
        store_c_lds<8, SA, true>(Bt, acc, lane);
    }
    {
        f32x4 acc[4];
        init_acc<4>(acc, bm2, lane);
        mfma_pass<4, 4, SA>(Bt, Wm2f, lane, acc);
        store_c_global<4, 64, false, true>(Sc, acc, rowbase, nN, lane);
    }
}

// fallback front
__global__ __launch_bounds__(256) void front_kernel(
    const float* __restrict__ X,
    const u16* __restrict__ W1f,
    const u16* __restrict__ Wm1f, const float* __restrict__ bm1,
    const u16* __restrict__ Wm2f, const float* __restrict__ bm2,
    u16* __restrict__ T1, u16* __restrict__ Sc, int nN)
{
    constexpr int SA = 136;
    __shared__ __align__(16) u16 As[4 * 16 * SA];
    __shared__ __align__(16) u16 Bs[4 * 16 * SA];
    int tid = threadIdx.x, w = tid >> 6, lane = tid & 63;
    int rowbase = blockIdx.x * 64 + w * 16;
    u16* At = As + w * 16 * SA;
    u16* Bt = Bs + w * 16 * SA;
    stage_cvt_tile<SA>(At, X, rowbase, nN, lane);
    {
        f32x4 acc[8];
        init_acc<8>(acc, nullptr, lane);
        mfma_pass<4, 8, SA>(At, W1f, lane, acc);
        store_c_global<8, 128, false, true>(T1, acc, rowbase, nN, lane);
    }
    {
        f32x4 acc[8];
        init_acc<8>(acc, bm1, lane);
        mfma_pass<4, 8, SA>(At, Wm1f, lane, acc);
        store_c_lds<8, SA, true>(Bt, acc, lane);
    }
    {
        f32x4 acc[4];
        init_acc<4>(acc, bm2, lane);
        mfma_pass<4, 4, SA>(Bt, Wm2f, lane, acc);
        store_c_global<4, 64, false, true>(Sc, acc, rowbase, nN, lane);
    }
}

// ---------------------------------------------------------------------------
// K5: level-2 row-sort, 512 threads, LDS-staged segment (single pl1 read).
// ---------------------------------------------------------------------------
__global__ __launch_bounds__(512) void sort_bucket2(
    const int2* __restrict__ pl1, const int* __restrict__ C,
    const int* __restrict__ boff, int2* __restrict__ pairs,
    int* __restrict__ rowptr, int E, int nN, int NBUK)
{
    __shared__ int2 sseg[SCAP];
    __shared__ int hist[BROWS], s[BROWS], cur[BROWS];
    int b = blockIdx.x, tid = threadIdx.x;
    int f0 = b * NBLK;
    int segb = C[f0] + boff[f0 >> 10];
    int sege;
    if (b + 1 < NBUK) {
        int f1 = (b + 1) * NBLK;
        sege = C[f1] + boff[f1 >> 10];
    } else sege = E;
    int seg = sege - segb;
    int stg = min(seg, SCAP);

    for (int i = tid; i < stg; i += 512) sseg[i] = pl1[segb + i];
    if (tid < BROWS) hist[tid] = 0;
    __syncthreads();
    for (int i = tid; i < stg; i += 512)
        atomicAdd(&hist[(u32)sseg[i].x >> 20], 1);
    for (int i = segb + stg + tid; i < sege; i += 512)
        atomicAdd(&hist[(u32)pl1[i].x >> 20], 1);
    __syncthreads();
    if (tid < BROWS) s[tid] = hist[tid];
    __syncthreads();
    for (int off = 1; off < BROWS; off <<= 1) {
        int t = 0;
        if (tid < BROWS && tid >= off) t = s[tid - off];
        __syncthreads();
        if (tid < BROWS) s[tid] += t;
        __syncthreads();
    }
    if (tid < BROWS) {
        int excl = segb + s[tid] - hist[tid];
        cur[tid] = excl;
        int row = b * BROWS + tid;
        if (row < nN) rowptr[row] = excl;
    }
    if (b == 0 && tid == 0) rowptr[nN] = E;
    __syncthreads();
    for (int i = tid; i < stg; i += 512) {
        int2 pr = sseg[i];
        int pos = atomicAdd(&cur[(u32)pr.x >> 20], 1);
        pairs[pos] = make_int2(pr.x & 0xFFFFF, pr.y);
    }
    for (int i = segb + stg + tid; i < sege; i += 512) {
        int2 pr = pl1[i];
        int pos = atomicAdd(&cur[(u32)pr.x >> 20], 1);
        pairs[pos] = make_int2(pr.x & 0xFFFFF, pr.y);
    }
}

// ---------------- fallback CSR build (large nN/E) --------------------------
__global__ __launch_bounds__(256) void rank_kernel(
    const int* __restrict__ dst, int* __restrict__ cnt,
    int* __restrict__ rank, int E)
{
    int i = blockIdx.x * blockDim.x + threadIdx.x;
    int ns = gridDim.x * blockDim.x;
    for (int e = i; e < E; e += ns) {
        int d = __builtin_nontemporal_load(dst + e);
        rank[e] = atomicAdd(&cnt[d], 1);
    }
}

__global__ __launch_bounds__(256) void scan3_fb(
    const int* __restrict__ data, const int* __restrict__ boff,
    int* __restrict__ rowptr, int n, int E)
{
    int i = blockIdx.x * blockDim.x + threadIdx.x;
    if (i < n) rowptr[i] = data[i] + boff[i >> 10];
    if (i == 0) rowptr[n] = E;
}

__global__ __launch_bounds__(256) void place_oct(
    const int* __restrict__ src, const int* __restrict__ dst,
    const float* __restrict__ w, const int* __restrict__ rank,
    const int* __restrict__ rowptr, int2* __restrict__ pairs, int E, int nN)
{
    int oct  = blockIdx.x & 7;
    int grp  = blockIdx.x >> 3;
    int ngrp = gridDim.x >> 3;
    int chunk = (nN + 7) / 8;
    int b0 = oct * chunk;
    int b1 = min(nN, b0 + chunk);
    int i  = grp * blockDim.x + threadIdx.x;
    int ns = ngrp * blockDim.x;
    for (int e = i; e < E; e += ns) {
        int d = __builtin_nontemporal_load(dst + e);
        if (d >= b0 && d < b1) {
            int pos  = rowptr[d] + __builtin_nontemporal_load(rank + e);
            int s    = __builtin_nontemporal_load(src + e);
            float ww = __builtin_nontemporal_load(w + e);
            pairs[pos] = make_int2(s, __float_as_int(ww));
        }
    }
}

// ---------------------------------------------------------------------------
template<int K, int NOUT, bool RELU, bool OBF16>
__global__ __launch_bounds__(256) void gemm_mfma(
    const u16* __restrict__ Xb, const u16* __restrict__ Wf,
    const float* __restrict__ bias, void* __restrict__ Y, int nN)
{
    constexpr int SA = K + 8;
    __shared__ __align__(16) u16 As[4 * 16 * SA];
    int tid = threadIdx.x, w = tid >> 6, lane = tid & 63;
    int rowbase = blockIdx.x * 64 + w * 16;
    u16* At = As + w * 16 * SA;
    stage_tile<K, SA>(At, Xb, rowbase, nN, lane, 0);
    f32x4 acc[NOUT / 16];
    init_acc<NOUT / 16>(acc, bias, lane);
    mfma_pass<K / 32, NOUT / 16, SA>(At, Wf, lane, acc);
    store_c_global<NOUT / 16, NOUT, RELU, OBF16>(Y, acc, rowbase, nN, lane);
}

// tail: out = relu([s_c|conv1|conv2]@Wh1+bh1) @ Wh2 + bh2  -> fp32
__global__ __launch_bounds__(256) void tail_mfma_kernel(
    const u16* __restrict__ Sc, const u16* __restrict__ C1, const u16* __restrict__ C2,
    const u16* __restrict__ Wh1f, const float* __restrict__ bh1,
    const u16* __restrict__ Wh2f, const float* __restrict__ bh2,
    float* __restrict__ out, int nN)
{
    constexpr int SA1 = 264, SA2 = 136;
    __shared__ __align__(16) u16 As[4 * 16 * SA1];
    __shared__ __align__(16) u16 Bs[4 * 16 * SA2];
    int tid = threadIdx.x, w = tid >> 6, lane = tid & 63;
    int rowbase = blockIdx.x * 64 + w * 16;
    u16* At = As + w * 16 * SA1;
    u16* Bt = Bs + w * 16 * SA2;
    stage_tile<64,  SA1>(At, Sc, rowbase, nN, lane, 0);
    stage_tile<128, SA1>(At, C1, rowbase, nN, lane, 64);
    stage_tile<64,  SA1>(At, C2, rowbase, nN, lane, 192);
    {
        f32x4 acc[8];
        init_acc<8>(acc, bh1, lane);
        mfma_pass<8, 8, SA1>(At, Wh1f, lane, acc);
        store_c_lds<8, SA2, true>(Bt, acc, lane);
    }
    {
        f32x4 acc[4];
        init_acc<4>(acc, bh2, lane);
        mfma_pass<4, 4, SA2>(Bt, Wh2f, lane, acc);
        store_c_global<4, 64, false, false>(out, acc, rowbase, nN, lane);
    }
}

// ---------------------------------------------------------------------------
// CSR SpMM gather (packed pairs), bf16 x, fp32 accum.
// Both widths: 2 rows per wave, 32-lane groups (avg degree ~32 fills them).
// ---------------------------------------------------------------------------
template<bool RELU>
__global__ __launch_bounds__(256) void spmm128_bf(
    const int* __restrict__ rowptr, const int2* __restrict__ pairs,
    const u16* __restrict__ x, u16* __restrict__ y, int nN)
{
    int lane = threadIdx.x & 63;
    int wp   = (blockIdx.x * blockDim.x + threadIdx.x) >> 6;
    int sub  = lane >> 5, sl = lane & 31;
    int row  = wp * 2 + sub;
    if (wp * 2 >= nN) return;
    bool live = row < nN;
    int rs = live ? rowptr[row] : 0;
    int re = live ? rowptr[row + 1] : 0;
    float a0 = 0.f, a1 = 0.f, a2 = 0.f, a3 = 0.f;
    for (int base = rs; base < re; base += 32) {
        int e = base + sl;
        int2 pr = make_int2(0, 0);
        if (e < re) pr = pairs[e];
        int cnt = min(32, re - base);
        int j = 0;
        for (; j + 4 <= cnt; j += 4) {
            int   s0 = __shfl(pr.x, j+0, 32), s1 = __shfl(pr.x, j+1, 32),
                  s2 = __shfl(pr.x, j+2, 32), s3 = __shfl(pr.x, j+3, 32);
            float w0 = __int_as_float(__shfl(pr.y, j+0, 32)),
                  w1 = __int_as_float(__shfl(pr.y, j+1, 32)),
                  w2 = __int_as_float(__shfl(pr.y, j+2, 32)),
                  w3 = __int_as_float(__shfl(pr.y, j+3, 32));
            uint2 u0 = *reinterpret_cast<const uint2*>(x + (size_t)s0 * 128 + sl * 4);
            uint2 u1 = *reinterpret_cast<const uint2*>(x + (size_t)s1 * 128 + sl * 4);
            uint2 u2 = *reinterpret_cast<const uint2*>(x + (size_t)s2 * 128 + sl * 4);
            uint2 u3 = *reinterpret_cast<const uint2*>(x + (size_t)s3 * 128 + sl * 4);
            a0 += w0 * bflo(u0.x); a1 += w0 * bfhi(u0.x);
            a2 += w0 * bflo(u0.y); a3 += w0 * bfhi(u0.y);
            a0 += w1 * bflo(u1.x); a1 += w1 * bfhi(u1.x);
            a2 += w1 * bflo(u1.y); a3 += w1 * bfhi(u1.y);
            a0 += w2 * bflo(u2.x); a1 += w2 * bfhi(u2.x);
            a2 += w2 * bflo(u2.y); a3 += w2 * bfhi(u2.y);
            a0 += w3 * bflo(u3.x); a1 += w3 * bfhi(u3.x);
            a2 += w3 * bflo(u3.y); a3 += w3 * bfhi(u3.y);
        }
        for (; j < cnt; ++j) {
            int   s = __shfl(pr.x, j, 32);
            float ww = __int_as_float(__shfl(pr.y, j, 32));
            uint2 u = *reinterpret_cast<const uint2*>(x + (size_t)s * 128 + sl * 4);
            a0 += ww * bflo(u.x); a1 += ww * bfhi(u.x);
            a2 += ww * bflo(u.y); a3 += ww * bfhi(u.y);
        }
    }
    if (live) {
        if (RELU) {
            a0 = fmaxf(a0, 0.f); a1 = fmaxf(a1, 0.f);
            a2 = fmaxf(a2, 0.f); a3 = fmaxf(a3, 0.f);
        }
        uint2 o;
        o.x = (u32)f2bf(a0) | ((u32)f2bf(a1) << 16);
        o.y = (u32)f2bf(a2) | ((u32)f2bf(a3) << 16);
        *reinterpret_cast<uint2*>(y + (size_t)row * 128 + sl * 4) = o;
    }
}

__global__ __launch_bounds__(256) void spmm64_bf(
    const int* __restrict__ rowptr, const int2* __restrict__ pairs,
    const u16* __restrict__ x, u16* __restrict__ y, int nN)
{
    int lane = threadIdx.x & 63;
    int wp   = (blockIdx.x * blockDim.x + threadIdx.x) >> 6;
    int sub  = lane >> 5, sl = lane & 31;
    int row  = wp * 2 + sub;
    if (wp * 2 >= nN) return;
    bool live = row < nN;
    int rs = live ? rowptr[row] : 0;
    int re = live ? rowptr[row + 1] : 0;
    float a0 = 0.f, a1 = 0.f;
    for (int base = rs; base < re; base += 32) {
        int e = base + sl;
        int2 pr = make_int2(0, 0);
        if (e < re) pr = pairs[e];
        int cnt = min(32, re - base);
        int j = 0;
        for (; j + 4 <= cnt; j += 4) {
            int   s0 = __shfl(pr.x, j+0, 32), s1 = __shfl(pr.x, j+1, 32),
                  s2 = __shfl(pr.x, j+2, 32), s3 = __shfl(pr.x, j+3, 32);
            float w0 = __int_as_float(__shfl(pr.y, j+0, 32)),
                  w1 = __int_as_float(__shfl(pr.y, j+1, 32)),
                  w2 = __int_as_float(__shfl(pr.y, j+2, 32)),
                  w3 = __int_as_float(__shfl(pr.y, j+3, 32));
            u32 u0 = *reinterpret_cast<const u32*>(x + (size_t)s0 * 64 + sl * 2);
            u32 u1 = *reinterpret_cast<const u32*>(x + (size_t)s1 * 64 + sl * 2);
            u32 u2 = *reinterpret_cast<const u32*>(x + (size_t)s2 * 64 + sl * 2);
            u32 u3 = *reinterpret_cast<const u32*>(x + (size_t)s3 * 64 + sl * 2);
            a0 += w0 * bflo(u0); a1 += w0 * bfhi(u0);
            a0 += w1 * bflo(u1); a1 += w1 * bfhi(u1);
            a0 += w2 * bflo(u2); a1 += w2 * bfhi(u2);
            a0 += w3 * bflo(u3); a1 += w3 * bfhi(u3);
        }
        for (; j < cnt; ++j) {
            int   s = __shfl(pr.x, j, 32);
            float ww = __int_as_float(__shfl(pr.y, j, 32));
            u32 u = *reinterpret_cast<const u32*>(x + (size_t)s * 64 + sl * 2);
            a0 += ww * bflo(u); a1 += ww * bfhi(u);
        }
    }
    if (live) {
        u32 o = (u32)f2bf(a0) | ((u32)f2bf(a1) << 16);
        *reinterpret_cast<u32*>(y + (size_t)row * 64 + sl * 2) = o;
    }
}

// ===========================================================================
extern "C" void kernel_launch(void* const* d_in, const int* in_sizes, int n_in,
                              void* d_out, int out_size, void* d_ws, size_t ws_size,
                              hipStream_t stream)
{
    const float* features = (const float*)d_in[0];
    const int*   esrc     = (const int*)d_in[1];
    const int*   edst     = (const int*)d_in[2];
    const float* ew       = (const float*)d_in[3];
    const float* W1  = (const float*)d_in[4];
    const float* W2  = (const float*)d_in[5];
    const float* Wm1 = (const float*)d_in[6];
    const float* bm1 = (const float*)d_in[7];
    const float* Wm2 = (const float*)d_in[8];
    const float* bm2 = (const float*)d_in[9];
    const float* Wh1 = (const float*)d_in[10];
    const float* bh1 = (const float*)d_in[11];
    const float* Wh2 = (const float*)d_in[12];
    const float* bh2 = (const float*)d_in[13];

    int nN = in_sizes[0] / D;   // 50000
    int E  = in_sizes[1];       // 1.6M
    float* out = (float*)d_out;

    // ---- workspace bump allocation ----
    char* base = (char*)d_ws;
    size_t off = 0;
    auto alloc = [&](size_t bytes) -> char* {
        char* p = base + off;
        off += (bytes + 255) & ~(size_t)255;
        return p;
    };
    u16*  conv2b = (u16*)alloc((size_t)nN * 64 * 2);   // C aliases this pre-spmm64
    u16*  t1b    = (u16*)alloc((size_t)nN * 128 * 2);  // t1b, later t2b
    u16*  conv1b = (u16*)alloc((size_t)nN * 128 * 2);  // pl1/rank alias pre-spmm128
    u16*  s_cb   = (u16*)alloc((size_t)nN * 64 * 2);
    int2* pairs  = (int2*)alloc((size_t)E * 8);
    int* rowptr  = (int*)alloc(((size_t)nN + 1) * 4);
    int* tmp     = (int*)alloc((size_t)nN * 4);        // fallback counts
    int* bsum    = (int*)alloc(4096 * 4);
    int* boff    = (int*)alloc(4096 * 4);
    u16* W1f  = (u16*)alloc(4 * 8 * 64 * 8 * 2);
    u16* Wm1f = (u16*)alloc(4 * 8 * 64 * 8 * 2);
    u16* W2f  = (u16*)alloc(4 * 4 * 64 * 8 * 2);
    u16* Wm2f = (u16*)alloc(4 * 4 * 64 * 8 * 2);
    u16* Wh2f = (u16*)alloc(4 * 4 * 64 * 8 * 2);
    u16* Wh1f = (u16*)alloc(8 * 8 * 64 * 8 * 2);
    u16* t2b = t1b;                  // [N,64] bf16, t1 dead after conv1 spmm
    int2* pl1 = (int2*)conv1b;       // level-1 pairs, dead before conv1 write
    int*  C   = (int*)conv2b;        // [NBUK*NBLK], dead before spmm64 writes conv2b

    int gGemm   = (nN + 63) / 64;
    int gSpmm1  = ((nN + 1) / 2 + 3) / 4;
    int gSpmm64 = ((nN + 1) / 2 + 3) / 4;

    int NBUK = (nN + BROWS - 1) >> BSH;
    bool mainPath = (NBUK <= 512) && (nN < (1 << 20)) &&
                    ((size_t)E * 8 <= (size_t)nN * 256) &&
                    ((size_t)NBUK * NBLK * 4 <= (size_t)nN * 128);
    if (mainPath) {
        int CE = (E + NBLK - 1) / NBLK;
        int n2 = NBUK * NBLK;
        int nb1 = (n2 + 1023) / 1024;
        // K1: repack + hist
        fused_prep<<<REPACK_BLKS + NBLK, 256, 0, stream>>>(
            W1, W1f, Wm1, Wm1f, W2, W2f, Wm2, Wm2f, Wh2, Wh2f, Wh1, Wh1f,
            edst, C, E, NBUK, CE);
        // K2/K3: scan
        scan1_kernel<<<nb1, 1024, 0, stream>>>(C, bsum, n2);
        scan_carry<<<1, 1024, 0, stream>>>(bsum, boff, nb1);
        // K4: front + place (boff added inline)
        front_place<<<gGemm + NBLK, 256, 0, stream>>>(
            features, W1f, Wm1f, bm1, Wm2f, bm2, t1b, s_cb, nN, gGemm,
            esrc, edst, ew, C, boff, pl1, E, NBUK, CE);
        // K5: row-sort buckets
        sort_bucket2<<<NBUK, 512, 0, stream>>>(pl1, C, boff, pairs, rowptr, E, nN, NBUK);
    } else {
        // fallback: rank/place + separate front
        int* rank = (int*)conv1b;
        fused_prep<<<REPACK_BLKS, 256, 0, stream>>>(
            W1, W1f, Wm1, Wm1f, W2, W2f, Wm2, Wm2f, Wh2, Wh2f, Wh1, Wh1f,
            edst, C, 0, 1, 1);   // repack-only (hist blocks absent)
        hipMemsetAsync(tmp, 0, (size_t)nN * 4, stream);
        rank_kernel<<<1024, 256, 0, stream>>>(edst, tmp, rank, E);
        int nb1 = (nN + 1023) / 1024;
        scan1_kernel<<<nb1, 1024, 0, stream>>>(tmp, bsum, nN);
        scan_carry<<<1, 1024, 0, stream>>>(bsum, boff, nb1);
        scan3_fb<<<(nN + 255) / 256, 256, 0, stream>>>(tmp, boff, rowptr, nN, E);
        place_oct<<<2048, 256, 0, stream>>>(esrc, edst, ew, rank, rowptr, pairs, E, nN);
        front_kernel<<<gGemm, 256, 0, stream>>>(features, W1f, Wm1f, bm1, Wm2f, bm2,
                                                t1b, s_cb, nN);
    }

    // conv1 = relu(A . t1)
    spmm128_bf<true><<<gSpmm1, 256, 0, stream>>>(rowptr, pairs, t1b, conv1b, nN);
    // t2 = conv1 @ W2
    gemm_mfma<128, 64, false, true><<<gGemm, 256, 0, stream>>>(conv1b, W2f, nullptr, t2b, nN);
    // conv2 = A . t2
    spmm64_bf<<<gSpmm64, 256, 0, stream>>>(rowptr, pairs, t2b, conv2b, nN);
    // out = relu([s_c|conv1|conv2]@Wh1+bh1)@Wh2+bh2
    tail_mfma_kernel<<<gGemm, 256, 0, stream>>>(s_cb, conv1b, conv2b,
                                                Wh1f, bh1, Wh2f, bh2, out, nN);
}